// Round 1
// baseline (3711.630 us; speedup 1.0000x reference)
//
#include <hip/hip_runtime.h>
#include <math.h>

constexpr int DIM     = 128;
constexpr int NCODES  = 1024;
constexpr int NSTAGES = 4;
constexpr int NVEC    = 16 * 8192;            // 131072 vectors
constexpr int QSIZE   = NVEC * DIM;           // floats in q output

// numpy pairwise sum of squares for exactly 128 elements:
// base case (n<=128): 8 accumulators, stride-8, tree combine.
// Squares must be rounded separately from the add -> contraction off.
template <typename PTR>
__device__ __forceinline__ float np_pairwise_sq128(PTR v) {
#pragma clang fp contract(off)
    float r[8];
#pragma unroll
    for (int j = 0; j < 8; ++j) {
        float sq = v[j] * v[j];
        r[j] = sq;
    }
#pragma unroll
    for (int i = 8; i < DIM; i += 8) {
#pragma unroll
        for (int j = 0; j < 8; ++j) {
            float sq = v[i + j] * v[i + j];
            r[j] = r[j] + sq;
        }
    }
    return ((r[0] + r[1]) + (r[2] + r[3])) + ((r[4] + r[5]) + (r[6] + r[7]));
}

__global__ __launch_bounds__(256, 1) void rvq_fp32_kernel(
        const float* __restrict__ x,
        const float* __restrict__ codebooks,
        float* __restrict__ out) {
    __shared__ float s_cnorm[NSTAGES * NCODES];

    const int tid = threadIdx.x;
    // Cooperative per-block codebook norms (np semantics), 4096 codes total.
    for (int i = tid; i < NSTAGES * NCODES; i += 256) {
        s_cnorm[i] = np_pairwise_sq128(codebooks + (size_t)i * DIM);
    }
    __syncthreads();

    const int vec = blockIdx.x * 256 + tid;
    const float* __restrict__ xv = x + (size_t)vec * DIM;

    // Residual lives entirely in VGPRs (all indexing compile-time constant).
    float r[DIM];
#pragma unroll
    for (int d = 0; d < DIM; d += 4) {
        float4 t = *reinterpret_cast<const float4*>(xv + d);
        r[d] = t.x; r[d + 1] = t.y; r[d + 2] = t.z; r[d + 3] = t.w;
    }

    for (int s = 0; s < NSTAGES; ++s) {
        const float rnorm = np_pairwise_sq128(r);
        const float* __restrict__ cb = codebooks + (size_t)s * NCODES * DIM;
        const float* __restrict__ cn = s_cnorm + s * NCODES;

        float best = INFINITY;
        int bidx = 0;

#pragma unroll 1
        for (int c = 0; c < NCODES; c += 4) {
            // Wave-uniform addresses (depend only on s, c) -> scalar loads.
            const float* __restrict__ c0 = cb + (size_t)c * DIM;
            float a0 = 0.f, a1 = 0.f, a2 = 0.f, a3 = 0.f;
#pragma unroll
            for (int d = 0; d < DIM; ++d) {
                const float rv = r[d];
                // Single-accumulator sequential FMA per code: mimics BLAS
                // sgemm k-sequential accumulation (bit-match goal).
                a0 = __builtin_fmaf(rv, c0[d],           a0);
                a1 = __builtin_fmaf(rv, c0[d + DIM],     a1);
                a2 = __builtin_fmaf(rv, c0[d + 2 * DIM], a2);
                a3 = __builtin_fmaf(rv, c0[d + 3 * DIM], a3);
            }
            // dist = (rnorm + cnorm) - 2*dot, numpy evaluation order.
            float d0 = (rnorm + cn[c + 0]) - 2.0f * a0;
            float d1 = (rnorm + cn[c + 1]) - 2.0f * a1;
            float d2 = (rnorm + cn[c + 2]) - 2.0f * a2;
            float d3 = (rnorm + cn[c + 3]) - 2.0f * a3;
            // Ascending order + strict < keeps the FIRST minimum (np.argmin).
            if (d0 < best) { best = d0; bidx = c + 0; }
            if (d1 < best) { best = d1; bidx = c + 1; }
            if (d2 < best) { best = d2; bidx = c + 2; }
            if (d3 < best) { best = d3; bidx = c + 3; }
        }

        // Gather chosen code (per-thread divergent row) and update residual.
        const float* __restrict__ ch = cb + (size_t)bidx * DIM;
#pragma unroll
        for (int d = 0; d < DIM; d += 4) {
            float4 cv = *reinterpret_cast<const float4*>(ch + d);
            r[d]     -= cv.x;
            r[d + 1] -= cv.y;
            r[d + 2] -= cv.z;
            r[d + 3] -= cv.w;
        }

        // Indices output: [n_stages, B, S] flattened after q; buffer is read
        // as float32 by the harness -> write the index as a float value.
        out[QSIZE + s * NVEC + vec] = (float)bidx;
    }

    // q = x - residual_final (differs from sum(chosen) only by ~1e-7 rounding).
#pragma unroll
    for (int d = 0; d < DIM; d += 4) {
        float4 t = *reinterpret_cast<const float4*>(xv + d);
        float4 o;
        o.x = t.x - r[d];
        o.y = t.y - r[d + 1];
        o.z = t.z - r[d + 2];
        o.w = t.w - r[d + 3];
        *reinterpret_cast<float4*>(out + (size_t)vec * DIM + d) = o;
    }
}

extern "C" void kernel_launch(void* const* d_in, const int* in_sizes, int n_in,
                              void* d_out, int out_size, void* d_ws, size_t ws_size,
                              hipStream_t stream) {
    const float* x         = (const float*)d_in[0];   // [16, 8192, 128] fp32
    const float* codebooks = (const float*)d_in[1];   // [4, 1024, 128] fp32
    float* out             = (float*)d_out;           // q (16.7M) ++ indices (524K)

    dim3 grid(NVEC / 256);
    dim3 block(256);
    rvq_fp32_kernel<<<grid, block, 0, stream>>>(x, codebooks, out);
}